// Round 8
// baseline (486.862 us; speedup 1.0000x reference)
//
#include <hip/hip_runtime.h>
#include <stdint.h>

#define BN 4
#define SN 4096
#define EN 256
#define PN 32
#define FN 1024
#define BS (BN*SN)   // 16384
#define PAUG 64      // 32 xs chans + aug (+ zero pad to 64)
#define ST  (SN/64)  // 64 s-tiles

typedef uint16_t bf16_t;
typedef short v4s  __attribute__((ext_vector_type(4)));
typedef short v8s  __attribute__((ext_vector_type(8)));
typedef __bf16 bf16x8 __attribute__((ext_vector_type(8)));
typedef float v4f   __attribute__((ext_vector_type(4)));

#define MFMA16(a,b,c) __builtin_amdgcn_mfma_f32_16x16x32_bf16(a,b,c,0,0,0)

__device__ __forceinline__ float b2f(bf16_t x){
    uint32_t u = ((uint32_t)x) << 16; float f; __builtin_memcpy(&f, &u, 4); return f;
}
__device__ __forceinline__ bf16_t f2b(float f){
    uint32_t u; __builtin_memcpy(&u, &f, 4);
    u += 0x7FFFu + ((u >> 16) & 1u);           // RNE
    return (bf16_t)(u >> 16);
}
__device__ __forceinline__ bf16x8 ldb8(const bf16_t* p){
    v8s r = *(const v8s*)p; return __builtin_bit_cast(bf16x8, r);
}
__device__ __forceinline__ float ldsc(const float* p){ return *p; }
__device__ __forceinline__ float ldsc(const bf16_t* p){ return b2f(*p); }
__device__ __forceinline__ void stsc(float* p, float v){ *p = v; }
__device__ __forceinline__ void stsc(bf16_t* p, float v){ *p = f2b(v); }

#if __has_builtin(__builtin_amdgcn_cvt_pk_bf16_f32)
typedef __bf16 bf16x2 __attribute__((ext_vector_type(2)));
__device__ __forceinline__ uint32_t pkbf16(float a, float b){
    bf16x2 r = __builtin_amdgcn_cvt_pk_bf16_f32(a, b);
    return __builtin_bit_cast(uint32_t, r);
}
#else
__device__ __forceinline__ uint32_t pkbf16(float a, float b){
    return (uint32_t)f2b(a) | ((uint32_t)f2b(b) << 16);
}
#endif

typedef const __attribute__((address_space(1))) uint32_t* glds_gp;
typedef __attribute__((address_space(3))) uint32_t* glds_lp;
__device__ __forceinline__ void glds16(const bf16_t* g, bf16_t* l){
    __builtin_amdgcn_global_load_lds((glds_gp)g, (glds_lp)l, 16, 0, 0);
}

// ---------------------------------------------------------------------------
// prep: one launch for (a) src fp32->bf16, (b) 4 weight cvts, (c) posxs.
// Grid: [0,4096) cvt-src | [4096,4736) cvt-weights | [4736,4800) posxs.
// posxs: key rows [xs, -sq/2, 1, 0..]; query rows pre-scaled by c1=log2e:
// [c1*xs, c1, -c1*sq/2, 0..] so the QK MFMA emits exp2-ready scores.
// ---------------------------------------------------------------------------
__global__ __launch_bounds__(256) void prep_kernel(
    const float* __restrict__ src, bf16_t* __restrict__ srcb,
    const float* __restrict__ Wv, bf16_t* __restrict__ Wvb,
    const float* __restrict__ Wo, bf16_t* __restrict__ Wob,
    const float* __restrict__ W1, bf16_t* __restrict__ W1b,
    const float* __restrict__ W2, bf16_t* __restrict__ W2b,
    const float* __restrict__ pos, const float* __restrict__ Wp,
    const float* __restrict__ bp,  const float* __restrict__ lsp,
    bf16_t* __restrict__ xk, bf16_t* __restrict__ xq)
{
    __shared__ float Wsh[PN*PN];
    __shared__ float bsh[PN];
    int bid = blockIdx.x;
    int tid = threadIdx.x;

    if (bid < 4736){
        const float* sp; bf16_t* dp; int off;
        if (bid < 4096){ sp = src; dp = srcb; off = (bid*256 + tid)*4; }
        else {
            int i = ((bid - 4096)*256 + tid)*4;
            if      (i <  65536){ sp=Wv; dp=Wvb; off=i; }
            else if (i < 131072){ sp=Wo; dp=Wob; off=i- 65536; }
            else if (i < 393216){ sp=W1; dp=W1b; off=i-131072; }
            else                { sp=W2; dp=W2b; off=i-393216; }
        }
        float4 f = *(const float4*)(sp + off);
        v4s o;
        o.x = (short)f2b(f.x); o.y = (short)f2b(f.y);
        o.z = (short)f2b(f.z); o.w = (short)f2b(f.w);
        *(v4s*)(dp + off) = o;
        return;
    }

    int pb = bid - 4736;          // 0..63
    int b  = pb >> 4;
    int s  = (pb & 15)*256 + tid;

    for (int i = tid; i < PN*PN; i += 256) Wsh[i] = Wp[i];
    if (tid < PN) bsh[tid] = bp[tid];
    __syncthreads();

    float inv_ls = 1.0f / lsp[0];
    const float c1f = 1.4426950408889634f;

    float col[PN];
    #pragma unroll
    for (int p = 0; p < PN; p++) col[p] = pos[((size_t)b*PN + p)*SN + s];

    uint16_t xb[PN], qb[PN];
    float sq = 0.f;
    #pragma unroll 4
    for (int o = 0; o < PN; o++){
        float pe = bsh[o];
        #pragma unroll
        for (int p = 0; p < PN; p++) pe += col[p] * Wsh[o*PN + p];
        float pv = pe * inv_ls;
        uint16_t h = f2b(pv);
        xb[o] = h;
        qb[o] = f2b(c1f * pv);
        float xr = b2f(h);
        sq += xr * xr;
    }

    size_t base = ((size_t)b*SN + s) * PAUG;
    v8s pk[8];
    #pragma unroll
    for (int c = 0; c < 4; c++)
        #pragma unroll
        for (int j = 0; j < 8; j++) ((short*)&pk[c])[j] = (short)xb[c*8 + j];
    #pragma unroll
    for (int c = 4; c < 8; c++)
        #pragma unroll
        for (int j = 0; j < 8; j++) ((short*)&pk[c])[j] = 0;
    ((short*)&pk[4])[0] = (short)f2b(-0.5f * sq);
    ((short*)&pk[4])[1] = (short)0x3F80;   // 1.0
    #pragma unroll
    for (int c = 0; c < 8; c++) *(v8s*)(xk + base + c*8) = pk[c];

    #pragma unroll
    for (int c = 0; c < 4; c++)
        #pragma unroll
        for (int j = 0; j < 8; j++) ((short*)&pk[c])[j] = (short)qb[c*8 + j];
    ((short*)&pk[4])[0] = (short)f2b(c1f);
    ((short*)&pk[4])[1] = (short)f2b(-0.5f * sq * c1f);
    #pragma unroll
    for (int c = 0; c < 8; c++) *(v8s*)(xq + base + c*8) = pk[c];
}

// ---------------------------------------------------------------------------
// gemm_a: out = A @ W^T (+bias, opt relu). Block 64m x 64n, 4 waves on m.
// Entire W-tile [64n x K] (K<=256) staged once via global_load_lds; one barrier.
// EPI 0: bias ; 1: relu ; 3: bias -> tiled-transposed store into
//        Vt2[b][e>>5][s>>6][e&31][s&63]  (4 KB tiles, attn-read-friendly)
// ---------------------------------------------------------------------------
template<int EPI, typename OutT>
__global__ __launch_bounds__(256) void gemm_a(
    const bf16_t* __restrict__ A, const bf16_t* __restrict__ W,
    const float* __restrict__ bias, OutT* __restrict__ out,
    bf16_t* __restrict__ vt, int M, int N, int K)
{
    __shared__ __align__(16) bf16_t Wt[8*2048];   // 32 KB max
    int tid = threadIdx.x;
    int lane = tid & 63, wv = tid >> 6, col = lane & 15, quad = lane >> 4;
    int m0 = blockIdx.x * 64, n0 = blockIdx.y * 64;
    int nck = K >> 5;

    const bf16_t* wsrc = W + (size_t)(n0 + (tid>>2))*K + (tid&3)*8;
    for (int r = 0; r < nck; r++)
        glds16(wsrc + r*32, Wt + r*2048 + tid*8);

    const bf16_t* Arow = A + (size_t)(m0 + wv*16 + col)*K + quad*8;

    v4f acc[4];
    #pragma unroll
    for (int t = 0; t < 4; t++) acc[t] = (v4f){0.f,0.f,0.f,0.f};

    __syncthreads();

    for (int c = 0; c < nck; c++){
        bf16x8 a = ldb8(Arow + c*32);
        #pragma unroll
        for (int t = 0; t < 4; t++){
            bf16x8 bf = ldb8(Wt + c*2048 + (t*16 + col)*32 + quad*8);
            acc[t] = MFMA16(a, bf, acc[t]);
        }
    }

    float bfv[4];
    #pragma unroll
    for (int t = 0; t < 4; t++) bfv[t] = bias[n0 + t*16 + col];

    if constexpr (EPI == 3){
        __shared__ uint16_t Tsh[64*74];
        #pragma unroll
        for (int r = 0; r < 4; r++)
            #pragma unroll
            for (int t = 0; t < 4; t++)
                Tsh[(wv*16 + quad*4 + r)*74 + t*16 + col] = f2b(acc[t][r] + bfv[t]);
        __syncthreads();
        int e = n0 + (tid >> 2), sc = tid & 3;
        int b = m0 >> 12;
        int sbase = m0 & (SN-1);
        v8s p0, p1;
        #pragma unroll
        for (int i = 0; i < 8; i++) ((short*)&p0)[i] = (short)Tsh[(sc*16 + i)*74 + (tid>>2)];
        #pragma unroll
        for (int i = 0; i < 8; i++) ((short*)&p1)[i] = (short)Tsh[(sc*16 + 8 + i)*74 + (tid>>2)];
        // tiled layout: ((e>>5)*ST + s>>6)*2048 + (e&31)*64 + (s&63)
        bf16_t* dst = vt + (size_t)b*EN*SN
                    + ((size_t)((e>>5)*ST + (sbase>>6)) << 11)
                    + ((e & 31) << 6) + sc*16;
        *(v8s*)dst = p0;
        *(v8s*)(dst + 8) = p1;
    } else {
        #pragma unroll
        for (int r = 0; r < 4; r++){
            int row = m0 + wv*16 + quad*4 + r;
            #pragma unroll
            for (int t = 0; t < 4; t++){
                float y = acc[t][r] + bfv[t];
                if constexpr (EPI == 1) y = fmaxf(y, 0.f);
                stsc(out + (size_t)row*N + n0 + t*16 + col, y);
            }
        }
    }
}

// ---------------------------------------------------------------------------
// gemm_b: out = A @ W^T + bias, K multiple of 128. Double-buffered W staging.
// ---------------------------------------------------------------------------
template<int RELU, typename OutT>
__global__ __launch_bounds__(256) void gemm_b(
    const bf16_t* __restrict__ A, const bf16_t* __restrict__ W,
    const float* __restrict__ bias, OutT* __restrict__ out,
    int N, int K)
{
    __shared__ __align__(16) bf16_t Wt[2][64*128];   // 2 x 16 KB
    int tid = threadIdx.x;
    int lane = tid & 63, wv = tid >> 6, col = lane & 15, quad = lane >> 4;
    int m0 = blockIdx.x * 64, n0 = blockIdx.y * 64;
    int nck = K >> 7;

    const bf16_t* wsrc = W + (size_t)(n0 + (tid>>2))*K + (tid&3)*8;
    const bf16_t* Arow = A + (size_t)(m0 + wv*16 + col)*K + quad*8;

    #pragma unroll
    for (int s = 0; s < 4; s++)
        glds16(wsrc + s*32, &Wt[0][s*2048 + tid*8]);

    v4f acc[4];
    #pragma unroll
    for (int t = 0; t < 4; t++) acc[t] = (v4f){0.f,0.f,0.f,0.f};

    __syncthreads();

    for (int c = 0; c < nck; c++){
        int cb = c & 1;
        if (c + 1 < nck){
            #pragma unroll
            for (int s = 0; s < 4; s++)
                glds16(wsrc + (c+1)*128 + s*32, &Wt[cb^1][s*2048 + tid*8]);
        }
        #pragma unroll
        for (int s = 0; s < 4; s++){
            bf16x8 a = ldb8(Arow + c*128 + s*32);
            #pragma unroll
            for (int t = 0; t < 4; t++){
                bf16x8 bf = ldb8(&Wt[cb][s*2048 + (t*16 + col)*32 + quad*8]);
                acc[t] = MFMA16(a, bf, acc[t]);
            }
        }
        __syncthreads();
    }

    float bfv[4];
    #pragma unroll
    for (int t = 0; t < 4; t++) bfv[t] = bias[n0 + t*16 + col];
    #pragma unroll
    for (int r = 0; r < 4; r++){
        int row = m0 + wv*16 + quad*4 + r;
        #pragma unroll
        for (int t = 0; t < 4; t++){
            float y = acc[t][r] + bfv[t];
            if constexpr (RELU) y = fmaxf(y, 0.f);
            stsc(out + (size_t)row*N + n0 + t*16 + col, y);
        }
    }
}

// ---------------------------------------------------------------------------
// ln_kernel: out = LayerNorm(y + res) * gamma + beta.  32 rows/block.
// ---------------------------------------------------------------------------
template<typename OutT, typename ResT>
__global__ __launch_bounds__(256) void ln_kernel(
    const bf16_t* __restrict__ y, const ResT* __restrict__ res,
    const float* __restrict__ gamma, const float* __restrict__ beta,
    OutT* __restrict__ out)
{
    int tid = threadIdx.x;
    int row = blockIdx.x * 32 + (tid >> 3);
    int l8  = tid & 7;
    size_t base = (size_t)row * EN;
    float v[32];
    float s1 = 0.f, s2 = 0.f;
    #pragma unroll
    for (int i = 0; i < 4; i++){
        int off = l8*8 + i*64;
        v8s a = *(const v8s*)(y + base + off);
        #pragma unroll
        for (int j = 0; j < 8; j++){
            float t = b2f((bf16_t)(uint16_t)a[j]) + ldsc(res + base + off + j);
            v[i*8 + j] = t; s1 += t; s2 += t*t;
        }
    }
    #pragma unroll
    for (int m = 1; m <= 4; m <<= 1){
        s1 += __shfl_xor(s1, m);
        s2 += __shfl_xor(s2, m);
    }
    float mu = s1 * (1.f/256.f);
    float rs = rsqrtf(s2 * (1.f/256.f) - mu*mu + 1e-5f);
    #pragma unroll
    for (int i = 0; i < 4; i++){
        int off = l8*8 + i*64;
        #pragma unroll
        for (int j = 0; j < 8; j++)
            stsc(out + base + off + j, (v[i*8+j]-mu)*rs*gamma[off+j] + beta[off+j]);
    }
}

// ---------------------------------------------------------------------------
// Attention round 8: Q=16/block, grid 1024, 4 blocks/CU. NO V LDS staging —
// PV B-frags read directly from the tiled Vt2 layout (consecutive-line
// global reads). Only the 4.5 KB w-tile goes through LDS (1 barrier/chunk).
// Waves: e-split (64 e each) for PV; 16-key slices each for QK.
// ---------------------------------------------------------------------------
__global__ __launch_bounds__(256, 4) void attn_kernel(
    const bf16_t* __restrict__ xk, const bf16_t* __restrict__ xq,
    const bf16_t* __restrict__ vt, const float* __restrict__ osp,
    bf16_t* __restrict__ ctx)
{
    __shared__ __align__(16) bf16_t Wtb[2][16*72];   // 4.5 KB
    __shared__ float densh[4][16];
    __shared__ float dent[16];

    int tid  = threadIdx.x;
    int lane = tid & 63;
    int wv   = tid >> 6;
    int col  = lane & 15;
    int quad = lane >> 4;

    // batch b pinned to XCD pair {2b,2b+1}
    int bid = blockIdx.x;
    int b   = (bid & 7) >> 1;
    int qi  = ((bid >> 3) << 1) | (bid & 1);
    int q0  = qi * 16;

    float k2 = 1.4426950408889634f * osp[0];

    const bf16_t* xkb = xk + (size_t)b * SN * PAUG;
    const bf16_t* xqb = xq + (size_t)b * SN * PAUG;
    const bf16_t* vtb = vt + (size_t)b * EN * SN;

    bf16x8 qf0 = ldb8(xqb + (size_t)(q0 + col)*PAUG + quad*8);
    bf16x8 qf1 = ldb8(xqb + (size_t)(q0 + col)*PAUG + 32 + quad*8);

    // per-et V base: eT = wv*2 + (et>>1); row-in-tile = (et&1)*16 + col
    const bf16_t* vbase[4];
    #pragma unroll
    for (int et = 0; et < 4; et++)
        vbase[et] = vtb + (size_t)(wv*2 + (et>>1))*ST*2048
                  + (((et&1)*16 + col) << 6) + quad*8;

    v4f acc[4];
    #pragma unroll
    for (int t = 0; t < 4; t++) acc[t] = (v4f){0.f,0.f,0.f,0.f};
    float den = 0.f;
    const v4f zero = (v4f){0.f,0.f,0.f,0.f};

    // QK + exp for one 64-key chunk (this wave's 16-key slice) -> buf
    auto qk_exp = [&](int c, bf16_t* buf){
        const bf16_t* krow = xkb + (size_t)(c*64 + wv*16 + col)*PAUG;
        bf16x8 kf0 = ldb8(krow + quad*8);
        bf16x8 kf1 = ldb8(krow + 32 + quad*8);
        v4f st = MFMA16(kf0, qf0, zero);
        st = MFMA16(kf1, qf1, st);
        #pragma unroll
        for (int rp = 0; rp < 2; rp++){
            float w0 = exp2f(fmaf(k2, exp2f(st[rp*2+0]), -k2));
            float w1 = exp2f(fmaf(k2, exp2f(st[rp*2+1]), -k2));
            den += w0 + w1;
            *(uint32_t*)&buf[col*72 + wv*16 + quad*4 + rp*2] = pkbf16(w0, w1);
        }
    };

    qk_exp(0, &Wtb[0][0]);
    __syncthreads();

    for (int c = 0; c < 64; c++){
        int cb = c & 1;
        // issue V loads for chunk c early (latency covered by qk_exp below)
        bf16x8 bf[4][2];
        #pragma unroll
        for (int et = 0; et < 4; et++)
            #pragma unroll
            for (int kg = 0; kg < 2; kg++)
                bf[et][kg] = ldb8(vbase[et] + c*2048 + kg*32);
        if (c < 63) qk_exp(c+1, &Wtb[cb^1][0]);
        bf16x8 af0 = ldb8(&Wtb[cb][col*72 + quad*8]);
        bf16x8 af1 = ldb8(&Wtb[cb][col*72 + 32 + quad*8]);
        #pragma unroll
        for (int et = 0; et < 4; et++){
            acc[et] = MFMA16(af0, bf[et][0], acc[et]);
            acc[et] = MFMA16(af1, bf[et][1], acc[et]);
        }
        __syncthreads();
    }

    den += __shfl_xor(den, 16);
    den += __shfl_xor(den, 32);
    if (lane < 16) densh[wv][lane] = den;
    __syncthreads();
    if (tid < 16)
        dent[tid] = 1.f / (densh[0][tid] + densh[1][tid] + densh[2][tid] + densh[3][tid]);
    __syncthreads();

    size_t obase = ((size_t)b*SN + q0) * EN + wv*64;
    #pragma unroll
    for (int r = 0; r < 4; r++){
        float inv = dent[quad*4 + r];
        #pragma unroll
        for (int et = 0; et < 4; et++)
            ctx[obase + (size_t)(quad*4 + r)*EN + et*16 + col] = f2b(acc[et][r] * inv);
    }
}

// ---------------------------------------------------------------------------
extern "C" void kernel_launch(void* const* d_in, const int* in_sizes, int n_in,
                              void* d_out, int out_size, void* d_ws, size_t ws_size,
                              hipStream_t stream)
{
    (void)in_sizes; (void)n_in; (void)out_size; (void)ws_size;
    const float* src  = (const float*)d_in[0];
    const float* pos  = (const float*)d_in[1];
    const float* Wpos = (const float*)d_in[2];
    const float* bpos = (const float*)d_in[3];
    const float* ls   = (const float*)d_in[4];
    const float* os   = (const float*)d_in[5];
    const float* Wv   = (const float*)d_in[6];
    const float* bv   = (const float*)d_in[7];
    const float* Wo   = (const float*)d_in[8];
    const float* bo   = (const float*)d_in[9];
    const float* W1   = (const float*)d_in[10];
    const float* b1   = (const float*)d_in[11];
    const float* W2   = (const float*)d_in[12];
    const float* b2   = (const float*)d_in[13];
    const float* g1   = (const float*)d_in[14];
    const float* be1  = (const float*)d_in[15];
    const float* g2   = (const float*)d_in[16];
    const float* be2  = (const float*)d_in[17];

    char* w = (char*)d_ws;
    bf16_t* xkb  = (bf16_t*)(w);                         // 2 MB [B,S,64]
    bf16_t* xqb  = (bf16_t*)(w + ( 2u<<20));             // 2 MB
    bf16_t* Wvb  = (bf16_t*)(w + ( 4u<<20));             // 128 KB
    bf16_t* Wob  = (bf16_t*)(w + ( 4u<<20) + (1u<<18));  // 128 KB
    bf16_t* W1b  = (bf16_t*)(w + ( 5u<<20));             // 512 KB
    bf16_t* W2b  = (bf16_t*)(w + ( 6u<<20));             // 512 KB
    bf16_t* srcb = (bf16_t*)(w + ( 8u<<20));             // 8 MB (alive thru ln1)
    bf16_t* y2   = (bf16_t*)(w + ( 8u<<20));             // aliases srcb (after ln1)
    bf16_t* vtg  = (bf16_t*)(w + (16u<<20));             // 8 MB tiled V (dead after attn)
    bf16_t* y1   = (bf16_t*)(w + (16u<<20));             // aliases vtg
    bf16_t* ctx  = (bf16_t*)(w + (24u<<20));             // 8 MB (dead after Wo-gemm)
    bf16_t* xws  = (bf16_t*)(w + (24u<<20));             // aliases ctx (after Wo-gemm)
    bf16_t* hws  = (bf16_t*)(w + (32u<<20));             // 32 MB

    prep_kernel<<<dim3(4800), 256, 0, stream>>>(
        src, srcb, Wv, Wvb, Wo, Wob, W1, W1b, W2, W2b,
        pos, Wpos, bpos, ls, xkb, xqb);

    // v = src @ Wv^T + bv  -> tiled store Vt2
    gemm_a<3, bf16_t><<<dim3(BS/64, EN/64), 256, 0, stream>>>(
        srcb, Wvb, bv, (bf16_t*)nullptr, vtg, BS, EN, EN);
    // ctx = softmax(os*exp(-0.5*d2)) @ v
    attn_kernel<<<dim3(1024), 256, 0, stream>>>(xkb, xqb, vtg, os, ctx);
    // y1 = ctx @ Wo^T + bo ; x = LN1(y1 + src)   (residual from bf16 srcb)
    gemm_a<0, bf16_t><<<dim3(BS/64, EN/64), 256, 0, stream>>>(
        ctx, Wob, bo, y1, (bf16_t*)nullptr, BS, EN, EN);
    ln_kernel<bf16_t, bf16_t><<<dim3(BS/32), 256, 0, stream>>>(y1, srcb, g1, be1, xws);
    // h = relu(x @ W1^T + b1)
    gemm_a<1, bf16_t><<<dim3(BS/64, FN/64), 256, 0, stream>>>(
        xws, W1b, b1, hws, (bf16_t*)nullptr, BS, FN, EN);
    // y2 = h @ W2^T + b2 ; out = LN2(y2 + x) -> fp32
    gemm_b<0, bf16_t><<<dim3(BS/64, EN/64), 256, 0, stream>>>(
        hws, W2b, b2, y2, EN, FN);
    ln_kernel<float, bf16_t><<<dim3(BS/32), 256, 0, stream>>>(y2, xws, g2, be2, (float*)d_out);
}

// Round 9
// 284.901 us; speedup vs baseline: 1.7089x; 1.7089x over previous
//
#include <hip/hip_runtime.h>
#include <stdint.h>

#define BN 4
#define SN 4096
#define EN 256
#define PN 32
#define FN 1024
#define BS (BN*SN)   // 16384
#define PAUG 64      // 32 xs chans + aug (+ zero pad to 64)

typedef uint16_t bf16_t;
typedef short v4s  __attribute__((ext_vector_type(4)));
typedef short v8s  __attribute__((ext_vector_type(8)));
typedef __bf16 bf16x8 __attribute__((ext_vector_type(8)));
typedef float v4f   __attribute__((ext_vector_type(4)));
typedef float v16f  __attribute__((ext_vector_type(16)));

#define MFMA16(a,b,c) __builtin_amdgcn_mfma_f32_16x16x32_bf16(a,b,c,0,0,0)
#define MFMA32(a,b,c) __builtin_amdgcn_mfma_f32_32x32x16_bf16(a,b,c,0,0,0)

__device__ __forceinline__ float b2f(bf16_t x){
    uint32_t u = ((uint32_t)x) << 16; float f; __builtin_memcpy(&f, &u, 4); return f;
}
__device__ __forceinline__ bf16_t f2b(float f){
    uint32_t u; __builtin_memcpy(&u, &f, 4);
    u += 0x7FFFu + ((u >> 16) & 1u);           // RNE
    return (bf16_t)(u >> 16);
}
__device__ __forceinline__ bf16x8 ldb8(const bf16_t* p){
    v8s r = *(const v8s*)p; return __builtin_bit_cast(bf16x8, r);
}
// 8-B-aligned load pair (for LDS rows with odd 8-B stride -> 2-way-free banks)
__device__ __forceinline__ bf16x8 ldb8u(const bf16_t* p){
    v4s lo = *(const v4s*)p;
    v4s hi = *(const v4s*)(p + 4);
    v8s r = __builtin_shufflevector(lo, hi, 0,1,2,3,4,5,6,7);
    return __builtin_bit_cast(bf16x8, r);
}
__device__ __forceinline__ float ldsc(const float* p){ return *p; }
__device__ __forceinline__ float ldsc(const bf16_t* p){ return b2f(*p); }
__device__ __forceinline__ void stsc(float* p, float v){ *p = v; }
__device__ __forceinline__ void stsc(bf16_t* p, float v){ *p = f2b(v); }

#if __has_builtin(__builtin_amdgcn_cvt_pk_bf16_f32)
typedef __bf16 bf16x2 __attribute__((ext_vector_type(2)));
__device__ __forceinline__ uint32_t pkbf16(float a, float b){
    bf16x2 r = __builtin_amdgcn_cvt_pk_bf16_f32(a, b);
    return __builtin_bit_cast(uint32_t, r);
}
#else
__device__ __forceinline__ uint32_t pkbf16(float a, float b){
    return (uint32_t)f2b(a) | ((uint32_t)f2b(b) << 16);
}
#endif

typedef const __attribute__((address_space(1))) uint32_t* glds_gp;
typedef __attribute__((address_space(3))) uint32_t* glds_lp;
__device__ __forceinline__ void glds16(const bf16_t* g, bf16_t* l){
    __builtin_amdgcn_global_load_lds((glds_gp)g, (glds_lp)l, 16, 0, 0);
}

// ---------------------------------------------------------------------------
// prep: (a) src fp32->bf16, (b) 4 weight cvts, (c) posxs. One launch.
// ---------------------------------------------------------------------------
__global__ __launch_bounds__(256) void prep_kernel(
    const float* __restrict__ src, bf16_t* __restrict__ srcb,
    const float* __restrict__ Wv, bf16_t* __restrict__ Wvb,
    const float* __restrict__ Wo, bf16_t* __restrict__ Wob,
    const float* __restrict__ W1, bf16_t* __restrict__ W1b,
    const float* __restrict__ W2, bf16_t* __restrict__ W2b,
    const float* __restrict__ pos, const float* __restrict__ Wp,
    const float* __restrict__ bp,  const float* __restrict__ lsp,
    bf16_t* __restrict__ xk, bf16_t* __restrict__ xq)
{
    __shared__ float Wsh[PN*PN];
    __shared__ float bsh[PN];
    int bid = blockIdx.x;
    int tid = threadIdx.x;

    if (bid < 4736){
        const float* sp; bf16_t* dp; int off;
        if (bid < 4096){ sp = src; dp = srcb; off = (bid*256 + tid)*4; }
        else {
            int i = ((bid - 4096)*256 + tid)*4;
            if      (i <  65536){ sp=Wv; dp=Wvb; off=i; }
            else if (i < 131072){ sp=Wo; dp=Wob; off=i- 65536; }
            else if (i < 393216){ sp=W1; dp=W1b; off=i-131072; }
            else                { sp=W2; dp=W2b; off=i-393216; }
        }
        float4 f = *(const float4*)(sp + off);
        v4s o;
        o.x = (short)f2b(f.x); o.y = (short)f2b(f.y);
        o.z = (short)f2b(f.z); o.w = (short)f2b(f.w);
        *(v4s*)(dp + off) = o;
        return;
    }

    int pb = bid - 4736;          // 0..63
    int b  = pb >> 4;
    int s  = (pb & 15)*256 + tid;

    for (int i = tid; i < PN*PN; i += 256) Wsh[i] = Wp[i];
    if (tid < PN) bsh[tid] = bp[tid];
    __syncthreads();

    float inv_ls = 1.0f / lsp[0];
    const float c1f = 1.4426950408889634f;

    float col[PN];
    #pragma unroll
    for (int p = 0; p < PN; p++) col[p] = pos[((size_t)b*PN + p)*SN + s];

    uint16_t xb[PN], qb[PN];
    float sq = 0.f;
    #pragma unroll 4
    for (int o = 0; o < PN; o++){
        float pe = bsh[o];
        #pragma unroll
        for (int p = 0; p < PN; p++) pe += col[p] * Wsh[o*PN + p];
        float pv = pe * inv_ls;
        uint16_t h = f2b(pv);
        xb[o] = h;
        qb[o] = f2b(c1f * pv);
        float xr = b2f(h);
        sq += xr * xr;
    }

    size_t base = ((size_t)b*SN + s) * PAUG;
    v8s pk[8];
    #pragma unroll
    for (int c = 0; c < 4; c++)
        #pragma unroll
        for (int j = 0; j < 8; j++) ((short*)&pk[c])[j] = (short)xb[c*8 + j];
    #pragma unroll
    for (int c = 4; c < 8; c++)
        #pragma unroll
        for (int j = 0; j < 8; j++) ((short*)&pk[c])[j] = 0;
    ((short*)&pk[4])[0] = (short)f2b(-0.5f * sq);
    ((short*)&pk[4])[1] = (short)0x3F80;   // 1.0
    #pragma unroll
    for (int c = 0; c < 8; c++) *(v8s*)(xk + base + c*8) = pk[c];

    #pragma unroll
    for (int c = 0; c < 4; c++)
        #pragma unroll
        for (int j = 0; j < 8; j++) ((short*)&pk[c])[j] = (short)qb[c*8 + j];
    ((short*)&pk[4])[0] = (short)f2b(c1f);
    ((short*)&pk[4])[1] = (short)f2b(-0.5f * sq * c1f);
    #pragma unroll
    for (int c = 0; c < 8; c++) *(v8s*)(xq + base + c*8) = pk[c];
}

// ---------------------------------------------------------------------------
// gemm_t: out = A @ W^T (+bias, opt relu). Block 64m x 64n, 4 waves on m.
// BOTH A and W tiles staged via global_load_lds in 64k chunks, double-buffered
// (32 KB LDS). XOR piece-swizzle folded into the per-lane SOURCE address so
// LDS rows are 128 B and all b128 fragment reads are 2-way (free).
// EPI 0: bias ; 1: relu ; 3: bias -> transposed store vt[b][e][s]
// ---------------------------------------------------------------------------
template<int EPI, typename OutT>
__global__ __launch_bounds__(256) void gemm_t(
    const bf16_t* __restrict__ A, const bf16_t* __restrict__ W,
    const float* __restrict__ bias, OutT* __restrict__ out,
    bf16_t* __restrict__ vt, int N, int K)
{
    __shared__ __align__(16) bf16_t At[2][4096];   // 2 x 8 KB
    __shared__ __align__(16) bf16_t Wt[2][4096];   // 2 x 8 KB
    int tid = threadIdx.x;
    int lane = tid & 63, wv = tid >> 6, col = lane & 15, quad = lane >> 4;
    int m0 = blockIdx.x * 64, n0 = blockIdx.y * 64;
    int nck = K >> 6;

    int srow = tid >> 3;                      // 0..31
    int spc  = (tid & 7) ^ (srow & 7);        // swizzled source piece
    const bf16_t* asrc = A + (size_t)(m0 + srow)*K + spc*8;
    const bf16_t* wsrc = W + (size_t)(n0 + srow)*K + spc*8;

    v4f acc[4];
    #pragma unroll
    for (int t = 0; t < 4; t++) acc[t] = (v4f){0.f,0.f,0.f,0.f};

    // stage chunk 0
    glds16(asrc, &At[0][tid*8]);
    glds16(asrc + (size_t)32*K, &At[0][2048 + tid*8]);
    glds16(wsrc, &Wt[0][tid*8]);
    glds16(wsrc + (size_t)32*K, &Wt[0][2048 + tid*8]);
    __syncthreads();

    for (int c = 0; c < nck; c++){
        int cb = c & 1;
        if (c + 1 < nck){
            glds16(asrc + (c+1)*64, &At[cb^1][tid*8]);
            glds16(asrc + (size_t)32*K + (c+1)*64, &At[cb^1][2048 + tid*8]);
            glds16(wsrc + (c+1)*64, &Wt[cb^1][tid*8]);
            glds16(wsrc + (size_t)32*K + (c+1)*64, &Wt[cb^1][2048 + tid*8]);
        }
        #pragma unroll
        for (int kc = 0; kc < 2; kc++){
            int pc = ((kc*4 + quad) ^ (col & 7)) * 8;
            bf16x8 a = ldb8(&At[cb][(wv*16 + col)*64 + pc]);
            #pragma unroll
            for (int t = 0; t < 4; t++){
                bf16x8 b = ldb8(&Wt[cb][(t*16 + col)*64 + pc]);
                acc[t] = MFMA16(a, b, acc[t]);
            }
        }
        __syncthreads();
    }

    float bfv[4];
    #pragma unroll
    for (int t = 0; t < 4; t++) bfv[t] = bias[n0 + t*16 + col];

    if constexpr (EPI == 3){
        __shared__ uint16_t Tsh[64*74];
        #pragma unroll
        for (int r = 0; r < 4; r++)
            #pragma unroll
            for (int t = 0; t < 4; t++)
                Tsh[(wv*16 + quad*4 + r)*74 + t*16 + col] = f2b(acc[t][r] + bfv[t]);
        __syncthreads();
        int e = tid >> 2, sc = tid & 3;
        int b = m0 >> 12;
        int sl = (m0 & (SN-1)) + sc*16;
        v8s p0, p1;
        #pragma unroll
        for (int i = 0; i < 8; i++) ((short*)&p0)[i] = (short)Tsh[(sc*16 + i)*74 + e];
        #pragma unroll
        for (int i = 0; i < 8; i++) ((short*)&p1)[i] = (short)Tsh[(sc*16 + 8 + i)*74 + e];
        bf16_t* dst = vt + ((size_t)b*EN + n0 + e)*SN + sl;
        *(v8s*)dst = p0;
        *(v8s*)(dst + 8) = p1;
    } else {
        #pragma unroll
        for (int r = 0; r < 4; r++){
            int row = m0 + wv*16 + quad*4 + r;
            #pragma unroll
            for (int t = 0; t < 4; t++){
                float y = acc[t][r] + bfv[t];
                if constexpr (EPI == 1) y = fmaxf(y, 0.f);
                stsc(out + (size_t)row*N + n0 + t*16 + col, y);
            }
        }
    }
}

// ---------------------------------------------------------------------------
// ln_kernel: out = LayerNorm(y + res) * gamma + beta.  32 rows/block.
// ---------------------------------------------------------------------------
template<typename OutT, typename ResT>
__global__ __launch_bounds__(256) void ln_kernel(
    const bf16_t* __restrict__ y, const ResT* __restrict__ res,
    const float* __restrict__ gamma, const float* __restrict__ beta,
    OutT* __restrict__ out)
{
    int tid = threadIdx.x;
    int row = blockIdx.x * 32 + (tid >> 3);
    int l8  = tid & 7;
    size_t base = (size_t)row * EN;
    float v[32];
    float s1 = 0.f, s2 = 0.f;
    #pragma unroll
    for (int i = 0; i < 4; i++){
        int off = l8*8 + i*64;
        v8s a = *(const v8s*)(y + base + off);
        #pragma unroll
        for (int j = 0; j < 8; j++){
            float t = b2f((bf16_t)(uint16_t)a[j]) + ldsc(res + base + off + j);
            v[i*8 + j] = t; s1 += t; s2 += t*t;
        }
    }
    #pragma unroll
    for (int m = 1; m <= 4; m <<= 1){
        s1 += __shfl_xor(s1, m);
        s2 += __shfl_xor(s2, m);
    }
    float mu = s1 * (1.f/256.f);
    float rs = rsqrtf(s2 * (1.f/256.f) - mu*mu + 1e-5f);
    #pragma unroll
    for (int i = 0; i < 4; i++){
        int off = l8*8 + i*64;
        #pragma unroll
        for (int j = 0; j < 8; j++)
            stsc(out + base + off + j, (v[i*8+j]-mu)*rs*gamma[off+j] + beta[off+j]);
    }
}

// ---------------------------------------------------------------------------
// Attention round 9: Q=32/block, grid 512, SINGLE-buffered V/w tiles ->
// 37.5 KB LDS -> 4 blocks/CU (16 waves). Per chunk: stage V(c) + QK/exp(c)
// -> barrier -> PV(c) -> barrier. Wtb stride 68 elems (2-way-free b64 reads).
// ---------------------------------------------------------------------------
__global__ __launch_bounds__(256, 4) void attn_kernel(
    const bf16_t* __restrict__ xk, const bf16_t* __restrict__ xq,
    const bf16_t* __restrict__ vt, const float* __restrict__ osp,
    bf16_t* __restrict__ ctx)
{
    __shared__ __align__(16) bf16_t Vl[256*64];   // 32 KB, piece-swizzled
    __shared__ __align__(16) bf16_t Wtb[32*68];   // 4.25 KB
    __shared__ float densh[4][32];
    __shared__ float dent[32];

    int tid  = threadIdx.x;
    int lane = tid & 63;
    int wv   = tid >> 6;
    int col  = lane & 15;
    int quad = lane >> 4;
    int l31  = lane & 31;
    int half = lane >> 5;

    // batch b pinned to XCD pair {2b,2b+1} -> its V slice L2-resident
    int bid = blockIdx.x;
    int b   = (bid & 7) >> 1;
    int qi  = ((bid >> 3) << 1) | (bid & 1);
    int q0  = qi * 32;

    float k2 = 1.4426950408889634f * osp[0];

    const bf16_t* xkb = xk + (size_t)b * SN * PAUG;
    const bf16_t* xqb = xq + (size_t)b * SN * PAUG;
    const bf16_t* vtb = vt + (size_t)b * EN * SN;

    bf16x8 qf[2][2];
    #pragma unroll
    for (int g2 = 0; g2 < 2; g2++)
        #pragma unroll
        for (int h = 0; h < 2; h++)
            qf[g2][h] = ldb8(xqb + (size_t)(q0 + g2*16 + col)*PAUG + h*32 + quad*8);

    int erow = tid >> 3;                     // 0..31
    int psw  = (tid & 7) ^ (erow & 7);       // swizzled global piece
    const bf16_t* vsrc = vtb + (size_t)erow * SN + psw*8;

    v16f acc[2];
    #pragma unroll
    for (int en = 0; en < 2; en++)
        #pragma unroll
        for (int i = 0; i < 16; i++) acc[en][i] = 0.f;
    float den[2] = {0.f, 0.f};
    const v4f zero = (v4f){0.f,0.f,0.f,0.f};

    for (int c = 0; c < 64; c++){
        // stage V(c) (drained by the barrier below; QK/exp covers latency)
        #pragma unroll
        for (int j = 0; j < 8; j++)
            glds16(vsrc + (size_t)j*32*SN + c*64, &Vl[j*2048 + tid*8]);
        // QK + exp for this wave's 16-key slice of chunk c
        {
            const bf16_t* krow = xkb + (size_t)(c*64 + wv*16 + col)*PAUG;
            bf16x8 kf0 = ldb8(krow + quad*8);
            bf16x8 kf1 = ldb8(krow + 32 + quad*8);
            #pragma unroll
            for (int g2 = 0; g2 < 2; g2++){
                v4f st = MFMA16(kf0, qf[g2][0], zero);
                st = MFMA16(kf1, qf[g2][1], st);
                #pragma unroll
                for (int rp = 0; rp < 2; rp++){
                    float w0 = exp2f(fmaf(k2, exp2f(st[rp*2+0]), -k2));
                    float w1 = exp2f(fmaf(k2, exp2f(st[rp*2+1]), -k2));
                    den[g2] += w0 + w1;
                    *(uint32_t*)&Wtb[(g2*16+col)*68 + wv*16 + quad*4 + rp*2] = pkbf16(w0, w1);
                }
            }
        }
        __syncthreads();   // V(c) + Wtb(c) ready

        // PV chunk c: this wave's 64-e slice, 32x32x16 MFMAs
        bf16x8 af[4];
        #pragma unroll
        for (int subk = 0; subk < 4; subk++)
            af[subk] = ldb8u(&Wtb[l31*68 + subk*16 + half*8]);
        int sw = l31 & 7;
        #pragma unroll
        for (int en = 0; en < 2; en++){
            const bf16_t* vrow = &Vl[(wv*64 + en*32 + l31)*64];
            #pragma unroll
            for (int subk = 0; subk < 4; subk++){
                bf16x8 bf = ldb8(vrow + ((subk*2 + half) ^ sw)*8);
                acc[en] = MFMA32(af[subk], bf, acc[en]);
            }
        }
        __syncthreads();   // protect Vl/Wtb before next stage
    }

    #pragma unroll
    for (int g2 = 0; g2 < 2; g2++){
        den[g2] += __shfl_xor(den[g2], 16);
        den[g2] += __shfl_xor(den[g2], 32);
    }
    if (lane < 16){
        densh[wv][lane]      = den[0];
        densh[wv][16 + lane] = den[1];
    }
    __syncthreads();
    if (tid < 32)
        dent[tid] = 1.f / (densh[0][tid] + densh[1][tid] + densh[2][tid] + densh[3][tid]);
    __syncthreads();

    size_t obase = ((size_t)b*SN + q0) * EN + wv*64;
    #pragma unroll
    for (int rg = 0; rg < 16; rg++){
        int row = (rg & 3) + 8*(rg >> 2) + 4*half;
        float inv = dent[row];
        #pragma unroll
        for (int en = 0; en < 2; en++)
            ctx[obase + (size_t)row*EN + en*32 + l31] = f2b(acc[en][rg] * inv);
    }
}

// ---------------------------------------------------------------------------
extern "C" void kernel_launch(void* const* d_in, const int* in_sizes, int n_in,
                              void* d_out, int out_size, void* d_ws, size_t ws_size,
                              hipStream_t stream)
{
    (void)in_sizes; (void)n_in; (void)out_size; (void)ws_size;
    const float* src  = (const float*)d_in[0];
    const float* pos  = (const float*)d_in[1];
    const float* Wpos = (const float*)d_in[2];
    const float* bpos = (const float*)d_in[3];
    const float* ls   = (const float*)d_in[4];
    const float* os   = (const float*)d_in[5];
    const float* Wv   = (const float*)d_in[6];
    const float* bv   = (const float*)d_in[7];
    const float* Wo   = (const float*)d_in[8];
    const float* bo   = (const float*)d_in[9];
    const float* W1   = (const float*)d_in[10];
    const float* b1   = (const float*)d_in[11];
    const float* W2   = (const float*)d_in[12];
    const float* b2   = (const float*)d_in[13];
    const float* g1   = (const float*)d_in[14];
    const float* be1  = (const float*)d_in[15];
    const float* g2   = (const float*)d_in[16];
    const float* be2  = (const float*)d_in[17];

    char* w = (char*)d_ws;
    bf16_t* xkb  = (bf16_t*)(w);                         // 2 MB [B,S,64]
    bf16_t* xqb  = (bf16_t*)(w + ( 2u<<20));             // 2 MB
    bf16_t* Wvb  = (bf16_t*)(w + ( 4u<<20));             // 128 KB
    bf16_t* Wob  = (bf16_t*)(w + ( 4u<<20) + (1u<<18));  // 128 KB
    bf16_t* W1b  = (bf16_t*)(w + ( 5u<<20));             // 512 KB
    bf16_t* W2b  = (bf16_t*)(w + ( 6u<<20));             // 512 KB
    bf16_t* srcb = (bf16_t*)(w + ( 8u<<20));             // 8 MB (alive thru ln1)
    bf16_t* y2   = (bf16_t*)(w + ( 8u<<20));             // aliases srcb (after ln1)
    bf16_t* vtg  = (bf16_t*)(w + (16u<<20));             // 8 MB [B,E,S] (dead after attn)
    bf16_t* y1   = (bf16_t*)(w + (16u<<20));             // aliases vtg
    bf16_t* ctx  = (bf16_t*)(w + (24u<<20));             // 8 MB (dead after Wo-gemm)
    bf16_t* xws  = (bf16_t*)(w + (24u<<20));             // aliases ctx (after Wo-gemm)
    bf16_t* hws  = (bf16_t*)(w + (32u<<20));             // 32 MB

    prep_kernel<<<dim3(4800), 256, 0, stream>>>(
        src, srcb, Wv, Wvb, Wo, Wob, W1, W1b, W2, W2b,
        pos, Wpos, bpos, ls, xkb, xqb);

    // v = src @ Wv^T + bv  -> transposed store vt[b][e][s]
    gemm_t<3, bf16_t><<<dim3(BS/64, EN/64), 256, 0, stream>>>(
        srcb, Wvb, bv, (bf16_t*)nullptr, vtg, EN, EN);
    // ctx = softmax(os*exp(-0.5*d2)) @ v
    attn_kernel<<<dim3(512), 256, 0, stream>>>(xkb, xqb, vtg, os, ctx);
    // y1 = ctx @ Wo^T + bo ; x = LN1(y1 + src)
    gemm_t<0, bf16_t><<<dim3(BS/64, EN/64), 256, 0, stream>>>(
        ctx, Wob, bo, y1, (bf16_t*)nullptr, EN, EN);
    ln_kernel<bf16_t, bf16_t><<<dim3(BS/32), 256, 0, stream>>>(y1, srcb, g1, be1, xws);
    // h = relu(x @ W1^T + b1)
    gemm_t<1, bf16_t><<<dim3(BS/64, FN/64), 256, 0, stream>>>(
        xws, W1b, b1, hws, (bf16_t*)nullptr, FN, EN);
    // y2 = h @ W2^T + b2 ; out = LN2(y2 + x) -> fp32
    gemm_t<0, bf16_t><<<dim3(BS/64, EN/64), 256, 0, stream>>>(
        hws, W2b, b2, y2, (bf16_t*)nullptr, EN, FN);
    ln_kernel<float, bf16_t><<<dim3(BS/32), 256, 0, stream>>>(y2, xws, g2, be2, (float*)d_out);
}